// Round 1
// baseline (466.345 us; speedup 1.0000x reference)
//
#include <hip/hip_runtime.h>
#include <hip/hip_bf16.h>

// BERT self-attention, B=4 S=2048 H=16 Dh=64, fp32 in/out, bf16 MFMA compute.
// Pipeline: convert X->bf16 | transpose+convert W->Wt bf16
//           gemm_bt: Q=(X Wq+bq)*0.125, K=X Wk+bk, Vt=(X Wv+bv)^T
//           flash attention (QK^T -> online softmax -> P V) -> fp32 out.

typedef float  f32x4  __attribute__((ext_vector_type(4)));
typedef short  short8 __attribute__((ext_vector_type(8)));
typedef __bf16 bf16x8 __attribute__((ext_vector_type(8)));

#define AS1 __attribute__((address_space(1)))
#define AS3 __attribute__((address_space(3)))

__device__ __forceinline__ void gload_lds16(const void* g, void* l) {
    // async global->LDS, 16B per lane; LDS dest is wave-uniform base + lane*16
    __builtin_amdgcn_global_load_lds((const AS1 void*)g, (AS3 void*)l, 16, 0, 0);
}

__device__ __forceinline__ unsigned short f2bf(float f) {
    union { float f; unsigned int u; } v; v.f = f;
    unsigned int u = v.u;
    unsigned int r = (u + 0x7fffu + ((u >> 16) & 1u)) >> 16;   // RTNE
    return (unsigned short)r;
}

__device__ __forceinline__ f32x4 mfma16(short8 a, short8 b, f32x4 c) {
    return __builtin_amdgcn_mfma_f32_16x16x32_bf16(
        __builtin_bit_cast(bf16x8, a), __builtin_bit_cast(bf16x8, b), c, 0, 0, 0);
}

// ---------------- conversion kernels ----------------

__global__ void conv_x(const float* __restrict__ X, unsigned short* __restrict__ Xb, int n4) {
    int i = blockIdx.x * blockDim.x + threadIdx.x;
    int stride = gridDim.x * blockDim.x;
    for (; i < n4; i += stride) {
        float4 v = ((const float4*)X)[i];
        ushort4 o;
        o.x = f2bf(v.x); o.y = f2bf(v.y); o.z = f2bf(v.z); o.w = f2bf(v.w);
        ((ushort4*)Xb)[i] = o;
    }
}

// W[k][n] (1024x1024 f32) -> Wt[n][k] (bf16)
__global__ void conv_w_t(const float* __restrict__ Wq, const float* __restrict__ Wk,
                         const float* __restrict__ Wv,
                         unsigned short* __restrict__ Wqt, unsigned short* __restrict__ Wkt,
                         unsigned short* __restrict__ Wvt) {
    const float* W = (blockIdx.z == 0) ? Wq : (blockIdx.z == 1) ? Wk : Wv;
    unsigned short* Wt = (blockIdx.z == 0) ? Wqt : (blockIdx.z == 1) ? Wkt : Wvt;
    __shared__ unsigned short tile[64][65];
    int n0 = blockIdx.x * 64, k0 = blockIdx.y * 64;
    int t = threadIdx.x;
    int cr = t >> 6, cc = t & 63;
    for (int i = 0; i < 16; i++) {
        int row = i * 4 + cr;  // k offset
        tile[row][cc] = f2bf(W[(size_t)(k0 + row) * 1024 + n0 + cc]);
    }
    __syncthreads();
    for (int i = 0; i < 16; i++) {
        int row = i * 4 + cr;  // n offset
        Wt[(size_t)(n0 + row) * 1024 + k0 + cc] = tile[cc][row];
    }
}

// ---------------- GEMM: out[m][n] = sum_k A[m][k] * Bt[n][k] (+bias, epilogue per MODE) ----
// MODE 0: Q  -> out[((b*16+h)*2048+s)*64+d] = (acc+bq[n])*0.125   (m=token, n=h*64+d)
// MODE 1: K  -> same layout, no scale
// MODE 2: Vt -> out[m*N+n] = acc+bias[m]                           (m=feature, n=token)

template <int MODE>
__global__ __launch_bounds__(256)
void gemm_bt(const unsigned short* __restrict__ A, const unsigned short* __restrict__ Bt,
             const float* __restrict__ bias, unsigned short* __restrict__ out,
             int M, int N, int K) {
    __shared__ unsigned short Alds[128 * 32];
    __shared__ unsigned short Blds[128 * 32];
    int t = threadIdx.x;
    int m0 = blockIdx.y * 128, n0 = blockIdx.x * 128;
    int wid = t >> 6, lane = t & 63, g = lane >> 4, r16 = lane & 15;
    int wr = wid >> 1, wc = wid & 1;

    f32x4 acc[4][4] = {};

    const unsigned short* Ab = A + (size_t)(m0 + (t >> 2)) * K + (t & 3) * 8;
    const unsigned short* Bb = Bt + (size_t)(n0 + (t >> 2)) * K + (t & 3) * 8;

    for (int k0 = 0; k0 < K; k0 += 32) {
        gload_lds16(Ab + k0, Alds + wid * 512);
        gload_lds16(Ab + k0 + (size_t)64 * K, Alds + 2048 + wid * 512);
        gload_lds16(Bb + k0, Blds + wid * 512);
        gload_lds16(Bb + k0 + (size_t)64 * K, Blds + 2048 + wid * 512);
        __syncthreads();

        short8 af[4], bfr[4];
        for (int m = 0; m < 4; m++)
            af[m] = *(const short8*)&Alds[(wr * 64 + m * 16 + r16) * 32 + g * 8];
        for (int n = 0; n < 4; n++)
            bfr[n] = *(const short8*)&Blds[(wc * 64 + n * 16 + r16) * 32 + g * 8];
        for (int m = 0; m < 4; m++)
            for (int n = 0; n < 4; n++)
                acc[m][n] = mfma16(af[m], bfr[n], acc[m][n]);
        __syncthreads();
    }

    for (int m = 0; m < 4; m++) {
        int gmBase = m0 + wr * 64 + m * 16 + g * 4;
        for (int n = 0; n < 4; n++) {
            int gn = n0 + wc * 64 + n * 16 + r16;
            float bcol = (MODE == 2) ? 0.f : bias[gn];
            for (int r = 0; r < 4; r++) {
                int gm = gmBase + r;
                float v;
                if (MODE == 2) v = acc[m][n][r] + bias[gm];
                else           v = acc[m][n][r] + bcol;
                if (MODE == 0) v *= 0.125f;
                if (MODE == 2) {
                    out[(size_t)gm * N + gn] = f2bf(v);
                } else {
                    int b = gm >> 11, s = gm & 2047, h = gn >> 6, d = gn & 63;
                    out[((size_t)(b * 16 + h) * 2048 + s) * 64 + d] = f2bf(v);
                }
            }
        }
    }
}

// ---------------- flash attention ----------------
// Q,K: [B*H][S][64] bf16 (Q pre-scaled by 0.125); Vt: [1024][8192] bf16
//   (Vt[h*64+d][b*2048+s]); mask: [B][S] f32; out: [B][S][1024] f32.
// Block: 256 thr = 4 waves; each wave owns 16 q-rows; KV tile = 64.

__global__ __launch_bounds__(256)
void attn(const unsigned short* __restrict__ Qb, const unsigned short* __restrict__ Kb,
          const unsigned short* __restrict__ Vtb, const float* __restrict__ mask,
          float* __restrict__ out) {
    __shared__ unsigned short Kl[64 * 64];
    __shared__ unsigned short Vl[64 * 64];
    __shared__ unsigned short Pl[4][16 * 64];

    int t = threadIdx.x, wid = t >> 6, lane = t & 63, g = lane >> 4, r16 = lane & 15;
    int bh = blockIdx.y, b = bh >> 4, h = bh & 15;
    int q0 = blockIdx.x * 64 + wid * 16;

    // Q fragments, held in registers for the whole KV loop
    const unsigned short* Qrow = Qb + ((size_t)bh * 2048 + q0 + r16) * 64;
    short8 qf0 = *(const short8*)&Qrow[g * 8];
    short8 qf1 = *(const short8*)&Qrow[32 + g * 8];

    float mstat[4], lstat[4];
    f32x4 octx[4];
    for (int r = 0; r < 4; r++) { mstat[r] = -1e30f; lstat[r] = 0.f; }
    for (int n = 0; n < 4; n++) octx[n] = (f32x4){0.f, 0.f, 0.f, 0.f};

    const unsigned short* Kbase = Kb + (size_t)bh * 2048 * 64;
    const unsigned short* Vbase = Vtb + (size_t)(h * 64) * 8192 + b * 2048;
    const float* mrow = mask + b * 2048;

    for (int t0 = 0; t0 < 2048; t0 += 64) {
        // stage K tile [64 t][64 d] and Vt tile [64 d][64 t]
        const unsigned short* gK = Kbase + (size_t)(t0 + (t >> 3)) * 64 + (t & 7) * 8;
        gload_lds16(gK, Kl + wid * 512);
        gload_lds16(gK + (size_t)32 * 64, Kl + 2048 + wid * 512);
        const unsigned short* gV = Vbase + (size_t)(t >> 3) * 8192 + t0 + (t & 7) * 8;
        gload_lds16(gV, Vl + wid * 512);
        gload_lds16(gV + (size_t)32 * 8192, Vl + 2048 + wid * 512);
        __syncthreads();

        // scores S = Q K^T (+mask); Q already scaled
        f32x4 s[4];
        for (int n = 0; n < 4; n++) {
            short8 kf0 = *(const short8*)&Kl[(n * 16 + r16) * 64 + g * 8];
            short8 kf1 = *(const short8*)&Kl[(n * 16 + r16) * 64 + 32 + g * 8];
            f32x4 a = (f32x4){0.f, 0.f, 0.f, 0.f};
            a = mfma16(qf0, kf0, a);
            a = mfma16(qf1, kf1, a);
            float mv = mrow[t0 + n * 16 + r16];
            s[n] = a + mv;
        }

        // online softmax per q-row (row r_glob = g*4+r; reduce across 16 lanes of group g)
        for (int r = 0; r < 4; r++) {
            float cm = fmaxf(fmaxf(s[0][r], s[1][r]), fmaxf(s[2][r], s[3][r]));
            for (int off = 1; off < 16; off <<= 1) cm = fmaxf(cm, __shfl_xor(cm, off));
            float nm = fmaxf(mstat[r], cm);
            float corr = __expf(mstat[r] - nm);
            float rs = 0.f;
            for (int n = 0; n < 4; n++) {
                float p = __expf(s[n][r] - nm);
                s[n][r] = p;
                rs += p;
            }
            for (int off = 1; off < 16; off <<= 1) rs += __shfl_xor(rs, off);
            lstat[r] = lstat[r] * corr + rs;
            mstat[r] = nm;
            for (int n = 0; n < 4; n++) octx[n][r] *= corr;
        }

        // P -> wave-private LDS (C-layout -> A-fragment layout relay)
        unsigned short* Pw = &Pl[wid][0];
        for (int r = 0; r < 4; r++)
            for (int n = 0; n < 4; n++)
                Pw[(g * 4 + r) * 64 + n * 16 + r16] = f2bf(s[n][r]);

        // ctx += P * V  (A = P [16 q][64 t], Bt = Vt [d][t])
        short8 pa0 = *(const short8*)&Pw[r16 * 64 + g * 8];
        short8 pa1 = *(const short8*)&Pw[r16 * 64 + 32 + g * 8];
        for (int n = 0; n < 4; n++) {
            short8 v0 = *(const short8*)&Vl[(n * 16 + r16) * 64 + g * 8];
            short8 v1 = *(const short8*)&Vl[(n * 16 + r16) * 64 + 32 + g * 8];
            octx[n] = mfma16(pa0, v0, octx[n]);
            octx[n] = mfma16(pa1, v1, octx[n]);
        }
        __syncthreads();
    }

    // epilogue: out[b][s][h*64+d] = octx / l
    for (int r = 0; r < 4; r++) {
        float inv = 1.f / lstat[r];
        for (int n = 0; n < 4; n++) {
            out[((size_t)b * 2048 + q0 + g * 4 + r) * 1024 + h * 64 + n * 16 + r16] =
                octx[n][r] * inv;
        }
    }
}

// ---------------- launch ----------------

extern "C" void kernel_launch(void* const* d_in, const int* in_sizes, int n_in,
                              void* d_out, int out_size, void* d_ws, size_t ws_size,
                              hipStream_t stream) {
    const float* X    = (const float*)d_in[0];
    const float* mask = (const float*)d_in[1];
    const float* Wq   = (const float*)d_in[2];
    const float* bq   = (const float*)d_in[3];
    const float* Wk   = (const float*)d_in[4];
    const float* bk   = (const float*)d_in[5];
    const float* Wv   = (const float*)d_in[6];
    const float* bv   = (const float*)d_in[7];
    float* out = (float*)d_out;

    unsigned short* ws  = (unsigned short*)d_ws;
    unsigned short* Xb  = ws;                  // 8192*1024
    unsigned short* Wqt = Xb + 8388608;        // 1024*1024
    unsigned short* Wkt = Wqt + 1048576;
    unsigned short* Wvt = Wkt + 1048576;
    unsigned short* Qb  = Wvt + 1048576;       // 8192*1024
    unsigned short* Kb  = Qb + 8388608;
    unsigned short* Vtb = Kb + 8388608;        // [1024][8192]

    conv_x<<<2048, 256, 0, stream>>>(X, Xb, 2097152);
    conv_w_t<<<dim3(16, 16, 3), 256, 0, stream>>>(Wq, Wk, Wv, Wqt, Wkt, Wvt);

    gemm_bt<0><<<dim3(8, 64), 256, 0, stream>>>(Xb, Wqt, bq, Qb, 8192, 1024, 1024);
    gemm_bt<1><<<dim3(8, 64), 256, 0, stream>>>(Xb, Wkt, bk, Kb, 8192, 1024, 1024);
    gemm_bt<2><<<dim3(64, 8), 256, 0, stream>>>(Wvt, Xb, bv, Vtb, 1024, 8192, 1024);

    attn<<<dim3(32, 64), 256, 0, stream>>>(Qb, Kb, Vtb, mask, out);
}

// Round 2
// 329.775 us; speedup vs baseline: 1.4141x; 1.4141x over previous
//
#include <hip/hip_runtime.h>
#include <hip/hip_bf16.h>

// BERT self-attention, B=4 S=2048 H=16 Dh=64, fp32 in/out, bf16 MFMA compute.
// Round 2: attn rewritten — QBLK=32/wave, XOR-swizzled K/V/P LDS (both-sides
// rule), fixed-reference softmax (no online max, deferred row-sum), K/V
// double-buffer with 2-phase prefetch.

typedef float  f32x4  __attribute__((ext_vector_type(4)));
typedef short  short8 __attribute__((ext_vector_type(8)));
typedef __bf16 bf16x8 __attribute__((ext_vector_type(8)));

#define AS1 __attribute__((address_space(1)))
#define AS3 __attribute__((address_space(3)))

__device__ __forceinline__ void gload_lds16(const void* g, void* l) {
    __builtin_amdgcn_global_load_lds((const AS1 void*)g, (AS3 void*)l, 16, 0, 0);
}

__device__ __forceinline__ unsigned short f2bf(float f) {
    union { float f; unsigned int u; } v; v.f = f;
    unsigned int u = v.u;
    unsigned int r = (u + 0x7fffu + ((u >> 16) & 1u)) >> 16;   // RTNE
    return (unsigned short)r;
}

__device__ __forceinline__ unsigned short f2bf_fast(float f) {
    __bf16 h = (__bf16)f;
    return __builtin_bit_cast(unsigned short, h);
}

__device__ __forceinline__ f32x4 mfma16(short8 a, short8 b, f32x4 c) {
    return __builtin_amdgcn_mfma_f32_16x16x32_bf16(
        __builtin_bit_cast(bf16x8, a), __builtin_bit_cast(bf16x8, b), c, 0, 0, 0);
}

// ---------------- conversion kernels ----------------

__global__ void conv_x(const float* __restrict__ X, unsigned short* __restrict__ Xb, int n4) {
    int i = blockIdx.x * blockDim.x + threadIdx.x;
    int stride = gridDim.x * blockDim.x;
    for (; i < n4; i += stride) {
        float4 v = ((const float4*)X)[i];
        ushort4 o;
        o.x = f2bf(v.x); o.y = f2bf(v.y); o.z = f2bf(v.z); o.w = f2bf(v.w);
        ((ushort4*)Xb)[i] = o;
    }
}

// W[k][n] (1024x1024 f32) -> Wt[n][k] (bf16)
__global__ void conv_w_t(const float* __restrict__ Wq, const float* __restrict__ Wk,
                         const float* __restrict__ Wv,
                         unsigned short* __restrict__ Wqt, unsigned short* __restrict__ Wkt,
                         unsigned short* __restrict__ Wvt) {
    const float* W = (blockIdx.z == 0) ? Wq : (blockIdx.z == 1) ? Wk : Wv;
    unsigned short* Wt = (blockIdx.z == 0) ? Wqt : (blockIdx.z == 1) ? Wkt : Wvt;
    __shared__ unsigned short tile[64][65];
    int n0 = blockIdx.x * 64, k0 = blockIdx.y * 64;
    int t = threadIdx.x;
    int cr = t >> 6, cc = t & 63;
    for (int i = 0; i < 16; i++) {
        int row = i * 4 + cr;
        tile[row][cc] = f2bf(W[(size_t)(k0 + row) * 1024 + n0 + cc]);
    }
    __syncthreads();
    for (int i = 0; i < 16; i++) {
        int row = i * 4 + cr;
        Wt[(size_t)(n0 + row) * 1024 + k0 + cc] = tile[cc][row];
    }
}

// ---------------- GEMM (unchanged from round 1, verified) ----------------

template <int MODE>
__global__ __launch_bounds__(256)
void gemm_bt(const unsigned short* __restrict__ A, const unsigned short* __restrict__ Bt,
             const float* __restrict__ bias, unsigned short* __restrict__ out,
             int M, int N, int K) {
    __shared__ unsigned short Alds[128 * 32];
    __shared__ unsigned short Blds[128 * 32];
    int t = threadIdx.x;
    int m0 = blockIdx.y * 128, n0 = blockIdx.x * 128;
    int wid = t >> 6, lane = t & 63, g = lane >> 4, r16 = lane & 15;
    int wr = wid >> 1, wc = wid & 1;

    f32x4 acc[4][4] = {};

    const unsigned short* Ab = A + (size_t)(m0 + (t >> 2)) * K + (t & 3) * 8;
    const unsigned short* Bb = Bt + (size_t)(n0 + (t >> 2)) * K + (t & 3) * 8;

    for (int k0 = 0; k0 < K; k0 += 32) {
        gload_lds16(Ab + k0, Alds + wid * 512);
        gload_lds16(Ab + k0 + (size_t)64 * K, Alds + 2048 + wid * 512);
        gload_lds16(Bb + k0, Blds + wid * 512);
        gload_lds16(Bb + k0 + (size_t)64 * K, Blds + 2048 + wid * 512);
        __syncthreads();

        short8 af[4], bfr[4];
        for (int m = 0; m < 4; m++)
            af[m] = *(const short8*)&Alds[(wr * 64 + m * 16 + r16) * 32 + g * 8];
        for (int n = 0; n < 4; n++)
            bfr[n] = *(const short8*)&Blds[(wc * 64 + n * 16 + r16) * 32 + g * 8];
        for (int m = 0; m < 4; m++)
            for (int n = 0; n < 4; n++)
                acc[m][n] = mfma16(af[m], bfr[n], acc[m][n]);
        __syncthreads();
    }

    for (int m = 0; m < 4; m++) {
        int gmBase = m0 + wr * 64 + m * 16 + g * 4;
        for (int n = 0; n < 4; n++) {
            int gn = n0 + wc * 64 + n * 16 + r16;
            float bcol = (MODE == 2) ? 0.f : bias[gn];
            for (int r = 0; r < 4; r++) {
                int gm = gmBase + r;
                float v;
                if (MODE == 2) v = acc[m][n][r] + bias[gm];
                else           v = acc[m][n][r] + bcol;
                if (MODE == 0) v *= 0.125f;
                if (MODE == 2) {
                    out[(size_t)gm * N + gn] = f2bf(v);
                } else {
                    int b = gm >> 11, s = gm & 2047, h = gn >> 6, d = gn & 63;
                    out[((size_t)(b * 16 + h) * 2048 + s) * 64 + d] = f2bf(v);
                }
            }
        }
    }
}

// ---------------- flash attention ----------------
// Q,K: [B*H][S][64] bf16 (Q pre-scaled by 0.125); Vt: [1024][8192] bf16;
// mask: [B][1][1][S] f32; out: [B][S][1024] f32.
// Block: 256 thr = 4 waves; wave owns 32 q-rows (2 row-blocks); KV tile 64.
// LDS tiles logical [64 rows][64 cols] bf16; storage swizzled:
//   addr_shorts(row, col) = row*64 + ((col>>3 ^ (row&7)) * 8) + (col&7)
// Staging pre-applies the inverse (same) XOR on the GLOBAL source address
// so gload_lds' linear dest produces the swizzled layout (rule #21).
// Softmax: fixed reference (exp(s), no max subtraction — scores bounded ~|6|),
// per-lane partial row-sums, single 16-lane reduction at the end.

__global__ __launch_bounds__(256)
void attn(const unsigned short* __restrict__ Qb, const unsigned short* __restrict__ Kb,
          const unsigned short* __restrict__ Vtb, const float* __restrict__ mask,
          float* __restrict__ out) {
    __shared__ unsigned short Kl[2][64 * 64];
    __shared__ unsigned short Vl[2][64 * 64];
    __shared__ unsigned short Pl[4][32 * 64];

    const int t = threadIdx.x, wid = t >> 6, lane = t & 63;
    const int g = lane >> 4, r16 = lane & 15, rsw = r16 & 7;
    const int bh = blockIdx.y, b = bh >> 4, h = bh & 15;
    const int q0 = blockIdx.x * 128 + wid * 32;

    // Q fragments: 2 row-blocks x 2 k-chunks, registers for whole KV loop
    short8 qf[2][2];
    #pragma unroll
    for (int m = 0; m < 2; m++) {
        const unsigned short* Qrow = Qb + ((size_t)bh * 2048 + q0 + m * 16 + r16) * 64;
        qf[m][0] = *(const short8*)&Qrow[g * 8];
        qf[m][1] = *(const short8*)&Qrow[32 + g * 8];
    }

    float lsum[2][4] = {};
    f32x4 octx[2][4] = {};

    // staging: thread t covers linear LDS chunk t*16B -> logical row=t>>3,
    // chunk=t&7; fetch from swizzled source chunk' = (t&7)^(row&7)
    const int srow = t >> 3;
    const int schk = (t & 7) ^ (srow & 7);
    const unsigned short* Kst = Kb + (size_t)bh * 2048 * 64 + srow * 64 + schk * 8;
    const unsigned short* Vst = Vtb + (size_t)(h * 64 + srow) * 8192 + (size_t)b * 2048 + schk * 8;
    const float* mrow = mask + (size_t)b * 2048;

    // prologue: stage tile 0
    gload_lds16(Kst,                     &Kl[0][wid * 512]);
    gload_lds16(Kst + (size_t)32 * 64,   &Kl[0][2048 + wid * 512]);
    gload_lds16(Vst,                     &Vl[0][wid * 512]);
    gload_lds16(Vst + (size_t)32 * 8192, &Vl[0][2048 + wid * 512]);
    asm volatile("s_waitcnt vmcnt(0)" ::: "memory");
    __syncthreads();

    int cur = 0;
    for (int t0 = 0; t0 < 2048; t0 += 64) {
        const int nxt = cur ^ 1;
        if (t0 + 64 < 2048) {   // issue next-tile staging; lands before end barrier
            const unsigned short* nK = Kst + (size_t)(t0 + 64) * 64;
            const unsigned short* nV = Vst + (t0 + 64);
            gload_lds16(nK,                     &Kl[nxt][wid * 512]);
            gload_lds16(nK + (size_t)32 * 64,   &Kl[nxt][2048 + wid * 512]);
            gload_lds16(nV,                     &Vl[nxt][wid * 512]);
            gload_lds16(nV + (size_t)32 * 8192, &Vl[nxt][2048 + wid * 512]);
        }
        const unsigned short* K_ = Kl[cur];
        const unsigned short* V_ = Vl[cur];
        unsigned short* Pw = Pl[wid];

        // QK^T + exp + P relay (per key-block n)
        #pragma unroll
        for (int n = 0; n < 4; n++) {
            const int krow = n * 16 + r16;
            short8 kf0 = *(const short8*)&K_[krow * 64 + ((g ^ rsw) * 8)];
            short8 kf1 = *(const short8*)&K_[krow * 64 + (((4 + g) ^ rsw) * 8)];
            f32x4 s0 = mfma16(qf[0][0], kf0, (f32x4){0.f, 0.f, 0.f, 0.f});
            s0 = mfma16(qf[0][1], kf1, s0);
            f32x4 s1 = mfma16(qf[1][0], kf0, (f32x4){0.f, 0.f, 0.f, 0.f});
            s1 = mfma16(qf[1][1], kf1, s1);
            const float mv = mrow[t0 + krow];
            const int chk = n * 2 + (r16 >> 3);
            #pragma unroll
            for (int r = 0; r < 4; r++) {
                float p0 = __expf(s0[r] + mv);
                float p1 = __expf(s1[r] + mv);
                lsum[0][r] += p0;
                lsum[1][r] += p1;
                const int row0 = g * 4 + r;        // rows 0..15 (m=0)
                const int row1 = 16 + row0;        // rows 16..31 (m=1), same low3 bits
                const int sc = (chk ^ (row0 & 7)) * 8 + rsw;
                Pw[row0 * 64 + sc] = f2bf_fast(p0);
                Pw[row1 * 64 + sc] = f2bf_fast(p1);
            }
        }

        // P A-fragments (same-wave LDS relay; DS ops are wave-ordered)
        short8 pa00 = *(const short8*)&Pw[r16 * 64 + ((g ^ rsw) * 8)];
        short8 pa01 = *(const short8*)&Pw[r16 * 64 + (((4 + g) ^ rsw) * 8)];
        short8 pa10 = *(const short8*)&Pw[(16 + r16) * 64 + ((g ^ rsw) * 8)];
        short8 pa11 = *(const short8*)&Pw[(16 + r16) * 64 + (((4 + g) ^ rsw) * 8)];

        // ctx += P * V
        #pragma unroll
        for (int n = 0; n < 4; n++) {
            const int vrow = n * 16 + r16;
            short8 v0 = *(const short8*)&V_[vrow * 64 + ((g ^ rsw) * 8)];
            short8 v1 = *(const short8*)&V_[vrow * 64 + (((4 + g) ^ rsw) * 8)];
            octx[0][n] = mfma16(pa00, v0, octx[0][n]);
            octx[0][n] = mfma16(pa01, v1, octx[0][n]);
            octx[1][n] = mfma16(pa10, v0, octx[1][n]);
            octx[1][n] = mfma16(pa11, v1, octx[1][n]);
        }

        asm volatile("s_waitcnt vmcnt(0)" ::: "memory");
        __syncthreads();
        cur = nxt;
    }

    // epilogue: reduce row sums across the 16-lane group, normalize, store
    #pragma unroll
    for (int m = 0; m < 2; m++) {
        #pragma unroll
        for (int r = 0; r < 4; r++) {
            float l = lsum[m][r];
            l += __shfl_xor(l, 1);
            l += __shfl_xor(l, 2);
            l += __shfl_xor(l, 4);
            l += __shfl_xor(l, 8);
            const float inv = 1.f / l;
            const int row = q0 + m * 16 + g * 4 + r;
            #pragma unroll
            for (int n = 0; n < 4; n++) {
                out[((size_t)b * 2048 + row) * 1024 + h * 64 + n * 16 + r16] =
                    octx[m][n][r] * inv;
            }
        }
    }
}

// ---------------- launch ----------------

extern "C" void kernel_launch(void* const* d_in, const int* in_sizes, int n_in,
                              void* d_out, int out_size, void* d_ws, size_t ws_size,
                              hipStream_t stream) {
    const float* X    = (const float*)d_in[0];
    const float* mask = (const float*)d_in[1];
    const float* Wq   = (const float*)d_in[2];
    const float* bq   = (const float*)d_in[3];
    const float* Wk   = (const float*)d_in[4];
    const float* bk   = (const float*)d_in[5];
    const float* Wv   = (const float*)d_in[6];
    const float* bv   = (const float*)d_in[7];
    float* out = (float*)d_out;

    unsigned short* ws  = (unsigned short*)d_ws;
    unsigned short* Xb  = ws;                  // 8192*1024
    unsigned short* Wqt = Xb + 8388608;        // 1024*1024
    unsigned short* Wkt = Wqt + 1048576;
    unsigned short* Wvt = Wkt + 1048576;
    unsigned short* Qb  = Wvt + 1048576;       // 8192*1024
    unsigned short* Kb  = Qb + 8388608;
    unsigned short* Vtb = Kb + 8388608;        // [1024][8192]

    conv_x<<<2048, 256, 0, stream>>>(X, Xb, 2097152);
    conv_w_t<<<dim3(16, 16, 3), 256, 0, stream>>>(Wq, Wk, Wv, Wqt, Wkt, Wvt);

    gemm_bt<0><<<dim3(8, 64), 256, 0, stream>>>(Xb, Wqt, bq, Qb, 8192, 1024, 1024);
    gemm_bt<1><<<dim3(8, 64), 256, 0, stream>>>(Xb, Wkt, bk, Kb, 8192, 1024, 1024);
    gemm_bt<2><<<dim3(64, 8), 256, 0, stream>>>(Wvt, Xb, bv, Vtb, 1024, 8192, 1024);

    attn<<<dim3(16, 64), 256, 0, stream>>>(Qb, Kb, Vtb, mask, out);
}

// Round 6
// 278.768 us; speedup vs baseline: 1.6729x; 1.1830x over previous
//
#include <hip/hip_runtime.h>
#include <hip/hip_bf16.h>

// BERT self-attention, B=4 S=2048 H=16 Dh=64, fp32 in/out, bf16 MFMA compute.
// Round 6 (= round 4 kernel, resubmitted after two GPU acquisition timeouts):
// 32x32 swapped-QK^T attn (lane-local softmax) with the P->PV redistribution
// done via verified primitives only: (__bf16) pack + bit-ops and
// __shfl_xor(.,32) + selects (no permlane asm, no cvt_pk asm, no exp2
// builtin). __expf softmax, Q scaled by 0.125, raw mask. GEMMs: double-
// buffered 2-phase prefetch; Q & K fused via blockIdx.z.

typedef float  f32x4  __attribute__((ext_vector_type(4)));
typedef float  f32x16 __attribute__((ext_vector_type(16)));
typedef short  short8 __attribute__((ext_vector_type(8)));
typedef __bf16 bf16x8 __attribute__((ext_vector_type(8)));
typedef unsigned int uint4v __attribute__((ext_vector_type(4)));

#define AS1 __attribute__((address_space(1)))
#define AS3 __attribute__((address_space(3)))

__device__ __forceinline__ void gload_lds16(const void* g, void* l) {
    __builtin_amdgcn_global_load_lds((const AS1 void*)g, (AS3 void*)l, 16, 0, 0);
}

__device__ __forceinline__ unsigned short f2bf(float f) {
    union { float f; unsigned int u; } v; v.f = f;
    unsigned int u = v.u;
    unsigned int r = (u + 0x7fffu + ((u >> 16) & 1u)) >> 16;   // RTNE
    return (unsigned short)r;
}

__device__ __forceinline__ unsigned packbf(float a, float b) {
    // two RTNE bf16 converts + pack; compiler may fuse to v_cvt_pk_bf16_f32
    unsigned short lo = __builtin_bit_cast(unsigned short, (__bf16)a);
    unsigned short hh = __builtin_bit_cast(unsigned short, (__bf16)b);
    return (unsigned)lo | ((unsigned)hh << 16);
}

__device__ __forceinline__ f32x4 mfma16(short8 a, short8 b, f32x4 c) {
    return __builtin_amdgcn_mfma_f32_16x16x32_bf16(
        __builtin_bit_cast(bf16x8, a), __builtin_bit_cast(bf16x8, b), c, 0, 0, 0);
}

__device__ __forceinline__ f32x16 mfma32(short8 a, short8 b, f32x16 c) {
    return __builtin_amdgcn_mfma_f32_32x32x16_bf16(
        __builtin_bit_cast(bf16x8, a), __builtin_bit_cast(bf16x8, b), c, 0, 0, 0);
}

__device__ __forceinline__ f32x16 mfma32u(uint4v a, short8 b, f32x16 c) {
    return __builtin_amdgcn_mfma_f32_32x32x16_bf16(
        __builtin_bit_cast(bf16x8, a), __builtin_bit_cast(bf16x8, b), c, 0, 0, 0);
}

// ---------------- conversion kernels ----------------

__global__ void conv_x(const float* __restrict__ X, unsigned short* __restrict__ Xb, int n4) {
    int i = blockIdx.x * blockDim.x + threadIdx.x;
    int stride = gridDim.x * blockDim.x;
    for (; i < n4; i += stride) {
        float4 v = ((const float4*)X)[i];
        ushort4 o;
        o.x = f2bf(v.x); o.y = f2bf(v.y); o.z = f2bf(v.z); o.w = f2bf(v.w);
        ((ushort4*)Xb)[i] = o;
    }
}

__global__ void conv_w_t(const float* __restrict__ Wq, const float* __restrict__ Wk,
                         const float* __restrict__ Wv,
                         unsigned short* __restrict__ Wqt, unsigned short* __restrict__ Wkt,
                         unsigned short* __restrict__ Wvt) {
    const float* W = (blockIdx.z == 0) ? Wq : (blockIdx.z == 1) ? Wk : Wv;
    unsigned short* Wt = (blockIdx.z == 0) ? Wqt : (blockIdx.z == 1) ? Wkt : Wvt;
    __shared__ unsigned short tile[64][65];
    int n0 = blockIdx.x * 64, k0 = blockIdx.y * 64;
    int t = threadIdx.x;
    int cr = t >> 6, cc = t & 63;
    for (int i = 0; i < 16; i++) {
        int row = i * 4 + cr;
        tile[row][cc] = f2bf(W[(size_t)(k0 + row) * 1024 + n0 + cc]);
    }
    __syncthreads();
    for (int i = 0; i < 16; i++) {
        int row = i * 4 + cr;
        Wt[(size_t)(n0 + row) * 1024 + k0 + cc] = tile[cc][row];
    }
}

// ---------------- GEMM: Q & K fused (z), double-buffered 2-phase ----------------

__global__ __launch_bounds__(256)
void gemm_qk(const unsigned short* __restrict__ A,
             const unsigned short* __restrict__ Bt0, const unsigned short* __restrict__ Bt1,
             const float* __restrict__ bias0, const float* __restrict__ bias1,
             unsigned short* __restrict__ o0, unsigned short* __restrict__ o1) {
    __shared__ unsigned short Alds[2][4096];
    __shared__ unsigned short Blds[2][4096];
    const int K = 1024;
    const int z = blockIdx.z;
    const unsigned short* Bt = z ? Bt1 : Bt0;
    const float* bias = z ? bias1 : bias0;
    unsigned short* out = z ? o1 : o0;
    const float scale = z ? 1.0f : 0.125f;

    int t = threadIdx.x;
    int m0 = blockIdx.y * 128, n0 = blockIdx.x * 128;
    int wid = t >> 6, lane = t & 63, g = lane >> 4, r16 = lane & 15;
    int wr = wid >> 1, wc = wid & 1;

    f32x4 acc[4][4] = {};

    const unsigned short* Ab = A + (size_t)(m0 + (t >> 2)) * K + (t & 3) * 8;
    const unsigned short* Bb = Bt + (size_t)(n0 + (t >> 2)) * K + (t & 3) * 8;

#define STAGE_G(buf, k0)                                              \
    gload_lds16(Ab + (k0), &Alds[buf][wid * 512]);                    \
    gload_lds16(Ab + (k0) + (size_t)64 * K, &Alds[buf][2048 + wid * 512]); \
    gload_lds16(Bb + (k0), &Blds[buf][wid * 512]);                    \
    gload_lds16(Bb + (k0) + (size_t)64 * K, &Blds[buf][2048 + wid * 512]);

    STAGE_G(0, 0)
    asm volatile("s_waitcnt vmcnt(0)" ::: "memory");
    __syncthreads();

    int cur = 0;
    for (int k0 = 0; k0 < K; k0 += 32) {
        if (k0 + 32 < K) { STAGE_G(cur ^ 1, k0 + 32) }
        short8 af[4], bfr[4];
        #pragma unroll
        for (int m = 0; m < 4; m++)
            af[m] = *(const short8*)&Alds[cur][(wr * 64 + m * 16 + r16) * 32 + g * 8];
        #pragma unroll
        for (int n = 0; n < 4; n++)
            bfr[n] = *(const short8*)&Blds[cur][(wc * 64 + n * 16 + r16) * 32 + g * 8];
        #pragma unroll
        for (int m = 0; m < 4; m++)
            #pragma unroll
            for (int n = 0; n < 4; n++)
                acc[m][n] = mfma16(af[m], bfr[n], acc[m][n]);
        asm volatile("s_waitcnt vmcnt(0)" ::: "memory");
        __syncthreads();
        cur ^= 1;
    }

    for (int m = 0; m < 4; m++) {
        int gmBase = m0 + wr * 64 + m * 16 + g * 4;
        for (int n = 0; n < 4; n++) {
            int gn = n0 + wc * 64 + n * 16 + r16;
            float bcol = bias[gn];
            for (int r = 0; r < 4; r++) {
                int gm = gmBase + r;
                float v = (acc[m][n][r] + bcol) * scale;
                int b = gm >> 11, s = gm & 2047, h = gn >> 6, d = gn & 63;
                out[((size_t)(b * 16 + h) * 2048 + s) * 64 + d] = f2bf(v);
            }
        }
    }
}

// ---------------- GEMM: Vt = Wvt x Xb^T (M=1024, N=8192), double-buffered ----

__global__ __launch_bounds__(256)
void gemm_v(const unsigned short* __restrict__ A, const unsigned short* __restrict__ Bt,
            const float* __restrict__ bias, unsigned short* __restrict__ out) {
    __shared__ unsigned short Alds[2][4096];
    __shared__ unsigned short Blds[2][4096];
    const int K = 1024, N = 8192;

    int t = threadIdx.x;
    int m0 = blockIdx.y * 128, n0 = blockIdx.x * 128;
    int wid = t >> 6, lane = t & 63, g = lane >> 4, r16 = lane & 15;
    int wr = wid >> 1, wc = wid & 1;

    f32x4 acc[4][4] = {};

    const unsigned short* Ab = A + (size_t)(m0 + (t >> 2)) * K + (t & 3) * 8;
    const unsigned short* Bb = Bt + (size_t)(n0 + (t >> 2)) * K + (t & 3) * 8;

    STAGE_G(0, 0)
    asm volatile("s_waitcnt vmcnt(0)" ::: "memory");
    __syncthreads();

    int cur = 0;
    for (int k0 = 0; k0 < K; k0 += 32) {
        if (k0 + 32 < K) { STAGE_G(cur ^ 1, k0 + 32) }
        short8 af[4], bfr[4];
        #pragma unroll
        for (int m = 0; m < 4; m++)
            af[m] = *(const short8*)&Alds[cur][(wr * 64 + m * 16 + r16) * 32 + g * 8];
        #pragma unroll
        for (int n = 0; n < 4; n++)
            bfr[n] = *(const short8*)&Blds[cur][(wc * 64 + n * 16 + r16) * 32 + g * 8];
        #pragma unroll
        for (int m = 0; m < 4; m++)
            #pragma unroll
            for (int n = 0; n < 4; n++)
                acc[m][n] = mfma16(af[m], bfr[n], acc[m][n]);
        asm volatile("s_waitcnt vmcnt(0)" ::: "memory");
        __syncthreads();
        cur ^= 1;
    }

    for (int m = 0; m < 4; m++) {
        int gmBase = m0 + wr * 64 + m * 16 + g * 4;
        for (int n = 0; n < 4; n++) {
            int gn = n0 + wc * 64 + n * 16 + r16;
            for (int r = 0; r < 4; r++) {
                int gm = gmBase + r;
                out[(size_t)gm * N + gn] = f2bf(acc[m][n][r] + bias[gm]);
            }
        }
    }
}

// ---------------- flash attention, 32x32 swapped ----------------
// Q,K: [B*H][S][64] bf16 (Q pre-scaled by 0.125); Vt: [1024][8192] bf16;
// mask: [B][S] f32 raw; out: [B][S][1024] f32.
// 256 thr = 4 waves; wave owns 64 q-rows. KV tile 64.
// QK^T swapped: St[t][q] = mfma32(K-frag, Q-frag), C-init = mask[t].
// C/D layout (32x32): col q = lane&31, row t = (reg&3)+8*(reg>>2)+4*(lane>>5).
// P->PV A-frag: pack adjacent-t pairs, exchange halves via __shfl_xor(.,32),
// select by hi. A-frag word w of t-chunk ts holds t = ts*16 + 8*hi + 2w,2w+1.

__global__ __launch_bounds__(256, 2)
void attn(const unsigned short* __restrict__ Qb, const unsigned short* __restrict__ Kb,
          const unsigned short* __restrict__ Vtb, const float* __restrict__ mask,
          float* __restrict__ out) {
    __shared__ unsigned short Kl[2][4096];
    __shared__ unsigned short Vl[2][4096];
    __shared__ float sums[4][64];

    const int t = threadIdx.x, wid = t >> 6, lane = t & 63;
    const int hi = lane >> 5, c = lane & 31;
    const int bh = blockIdx.x, b = bh >> 4, h = bh & 15;
    const int q0w = blockIdx.y * 256 + wid * 64;

    // Q fragments (B-operand): lane holds Q[q0w+qh*32+c][ds*16+hi*8 .. +7]
    short8 qf[2][4];
    #pragma unroll
    for (int qh = 0; qh < 2; qh++)
        #pragma unroll
        for (int ds = 0; ds < 4; ds++)
            qf[qh][ds] = *(const short8*)&Qb[((size_t)bh * 2048 + q0w + qh * 32 + c) * 64
                                             + ds * 16 + hi * 8];

    float lsum[2] = {0.f, 0.f};
    f32x16 ctx[2][2] = {};   // [qh][dblk]

    const int srow = t >> 3, schk = (t & 7) ^ (srow & 7);
    const unsigned short* Kst = Kb + (size_t)bh * 2048 * 64 + srow * 64 + schk * 8;
    const unsigned short* Vst = Vtb + (size_t)(h * 64 + srow) * 8192 + (size_t)b * 2048 + schk * 8;
    const float* mrow = mask + (size_t)b * 2048;

    gload_lds16(Kst,                       &Kl[0][wid * 512]);
    gload_lds16(Kst + (size_t)32 * 64,     &Kl[0][2048 + wid * 512]);
    gload_lds16(Vst,                       &Vl[0][wid * 512]);
    gload_lds16(Vst + (size_t)32 * 8192,   &Vl[0][2048 + wid * 512]);
    asm volatile("s_waitcnt vmcnt(0)" ::: "memory");
    __syncthreads();

    int cur = 0;
    for (int t0 = 0; t0 < 2048; t0 += 64) {
        if (t0 + 64 < 2048) {
            const unsigned short* nK = Kst + (size_t)(t0 + 64) * 64;
            const unsigned short* nV = Vst + (t0 + 64);
            gload_lds16(nK,                     &Kl[cur ^ 1][wid * 512]);
            gload_lds16(nK + (size_t)32 * 64,   &Kl[cur ^ 1][2048 + wid * 512]);
            gload_lds16(nV,                     &Vl[cur ^ 1][wid * 512]);
            gload_lds16(nV + (size_t)32 * 8192, &Vl[cur ^ 1][2048 + wid * 512]);
        }
        const unsigned short* K_ = Kl[cur];
        const unsigned short* V_ = Vl[cur];

        uint4v pa[2][4];   // [qh][t-chunk ts]
        #pragma unroll
        for (int kb = 0; kb < 2; kb++) {
            short8 kf[4];
            #pragma unroll
            for (int ds = 0; ds < 4; ds++) {
                const int row = kb * 32 + c;
                kf[ds] = *(const short8*)&K_[row * 64 + (((ds * 2 + hi) ^ (row & 7)) * 8)];
            }
            float4 m4[4];
            #pragma unroll
            for (int q = 0; q < 4; q++)
                m4[q] = *(const float4*)&mrow[t0 + kb * 32 + q * 8 + hi * 4];
            #pragma unroll
            for (int qh = 0; qh < 2; qh++) {
                f32x16 st;
                #pragma unroll
                for (int q = 0; q < 4; q++) {
                    st[q * 4 + 0] = m4[q].x; st[q * 4 + 1] = m4[q].y;
                    st[q * 4 + 2] = m4[q].z; st[q * 4 + 3] = m4[q].w;
                }
                #pragma unroll
                for (int ds = 0; ds < 4; ds++)
                    st = mfma32(kf[ds], qf[qh][ds], st);
                float p[16];
                #pragma unroll
                for (int r = 0; r < 16; r++) {
                    p[r] = __expf(st[r]);
                    lsum[qh] += p[r];
                }
                // cc[i] packs t-pair {crow(2i,hi), crow(2i,hi)+1} of this kb block
                unsigned cc[8], sx[8];
                #pragma unroll
                for (int i = 0; i < 8; i++) cc[i] = packbf(p[2 * i], p[2 * i + 1]);
                #pragma unroll
                for (int i = 0; i < 8; i++) sx[i] = __shfl_xor(cc[i], 32);
                // A-frag word w of chunk ts: t = ts*16 + 8*hi + {2w, 2w+1}
                pa[qh][kb * 2] = (uint4v){
                    hi ? sx[2] : cc[0], hi ? sx[3] : cc[1],
                    hi ? cc[2] : sx[0], hi ? cc[3] : sx[1]};
                pa[qh][kb * 2 + 1] = (uint4v){
                    hi ? sx[6] : cc[4], hi ? sx[7] : cc[5],
                    hi ? cc[6] : sx[4], hi ? cc[7] : sx[5]};
            }
        }
        #pragma unroll
        for (int db = 0; db < 2; db++) {
            #pragma unroll
            for (int ts = 0; ts < 4; ts++) {
                const int row = db * 32 + c;
                short8 vf = *(const short8*)&V_[row * 64 + (((ts * 2 + hi) ^ (row & 7)) * 8)];
                ctx[0][db] = mfma32u(pa[0][ts], vf, ctx[0][db]);
                ctx[1][db] = mfma32u(pa[1][ts], vf, ctx[1][db]);
            }
        }
        asm volatile("s_waitcnt vmcnt(0)" ::: "memory");
        __syncthreads();
        cur ^= 1;
    }

    // row sums: partial covers own hi-half t's; partner holds the rest
    #pragma unroll
    for (int qh = 0; qh < 2; qh++) {
        float tot = lsum[qh] + __shfl_xor(lsum[qh], 32);
        if (hi == 0) sums[wid][qh * 32 + c] = tot;
    }
    __syncthreads();
    #pragma unroll
    for (int qh = 0; qh < 2; qh++) {
        #pragma unroll
        for (int rg = 0; rg < 4; rg++) {
            float4 sv = *(const float4*)&sums[wid][qh * 32 + rg * 8 + hi * 4];
            float svf[4] = {sv.x, sv.y, sv.z, sv.w};
            #pragma unroll
            for (int r = 0; r < 4; r++) {
                const float inv = 1.f / svf[r];
                const int reg = rg * 4 + r;
                const int row = q0w + qh * 32 + rg * 8 + hi * 4 + r;
                out[((size_t)b * 2048 + row) * 1024 + h * 64 + c]      = ctx[qh][0][reg] * inv;
                out[((size_t)b * 2048 + row) * 1024 + h * 64 + 32 + c] = ctx[qh][1][reg] * inv;
            }
        }
    }
}

// ---------------- launch ----------------

extern "C" void kernel_launch(void* const* d_in, const int* in_sizes, int n_in,
                              void* d_out, int out_size, void* d_ws, size_t ws_size,
                              hipStream_t stream) {
    const float* X    = (const float*)d_in[0];
    const float* mask = (const float*)d_in[1];
    const float* Wq   = (const float*)d_in[2];
    const float* bq   = (const float*)d_in[3];
    const float* Wk   = (const float*)d_in[4];
    const float* bk   = (const float*)d_in[5];
    const float* Wv   = (const float*)d_in[6];
    const float* bv   = (const float*)d_in[7];
    float* out = (float*)d_out;

    unsigned short* ws  = (unsigned short*)d_ws;
    unsigned short* Xb  = ws;                  // 8192*1024 bf16
    unsigned short* Wqt = Xb + 8388608;        // 1024*1024
    unsigned short* Wkt = Wqt + 1048576;
    unsigned short* Wvt = Wkt + 1048576;
    unsigned short* Qb  = Wvt + 1048576;       // 8192*1024
    unsigned short* Kb  = Qb + 8388608;
    unsigned short* Vtb = Kb + 8388608;        // [1024][8192]

    conv_x<<<2048, 256, 0, stream>>>(X, Xb, 2097152);
    conv_w_t<<<dim3(16, 16, 3), 256, 0, stream>>>(Wq, Wk, Wv, Wqt, Wkt, Wvt);

    gemm_qk<<<dim3(8, 64, 2), 256, 0, stream>>>(Xb, Wqt, Wkt, bq, bk, Qb, Kb);
    gemm_v<<<dim3(64, 8), 256, 0, stream>>>(Wvt, Xb, bv, Vtb);

    attn<<<dim3(64, 8), 256, 0, stream>>>(Qb, Kb, Vtb, mask, out);
}